// Round 1
// baseline (518.875 us; speedup 1.0000x reference)
//
#include <hip/hip_runtime.h>
#include <hip/hip_bf16.h>
#include <math.h>

#define EPS 1e-5f

typedef __hip_bfloat16 bf16;
typedef short short8 __attribute__((ext_vector_type(8)));
typedef float float4v __attribute__((ext_vector_type(4)));

__device__ __forceinline__ float toF(float v) { return v; }
__device__ __forceinline__ float toF(bf16 v) { return __bfloat162float(v); }
__device__ __forceinline__ void stF(float* p, float v) { *p = v; }
__device__ __forceinline__ void stF(bf16* p, float v) { *p = __float2bfloat16(v); }
__device__ __forceinline__ short f2bs(float v) {
    bf16 b = __float2bfloat16(v);
    return *reinterpret_cast<short*>(&b);
}
__device__ __forceinline__ float bs2f(short s) {
    unsigned u = ((unsigned)(unsigned short)s) << 16;
    return __uint_as_float(u);
}

// ---------------- block reduction (blockDim.x == 256) ----------------
__device__ __forceinline__ float block_reduce_sum(float v) {
    __shared__ float s[256];
    int t = threadIdx.x;
    s[t] = v;
    __syncthreads();
    #pragma unroll
    for (int st = 128; st > 0; st >>= 1) {
        if (t < st) s[t] += s[t + st];
        __syncthreads();
    }
    float r = s[0];
    __syncthreads();
    return r;
}

// ---------------- ternarize -> bf16 {-1,0,+1} + fp32 alpha ----------------
__global__ void ternarize_kernel(const float* __restrict__ w, short* __restrict__ wt,
                                 float* __restrict__ alpha, int K) {
    int f = blockIdx.x;
    const float* wf = w + (size_t)f * K;
    short* wtf = wt + (size_t)f * K;

    float s = 0.f;
    for (int i = threadIdx.x; i < K; i += blockDim.x) s += fabsf(wf[i]);
    float total = block_reduce_sum(s);
    float delta = 0.7f * total / (float)K;

    float sm = 0.f, cm = 0.f;
    for (int i = threadIdx.x; i < K; i += blockDim.x) {
        float a = fabsf(wf[i]);
        if (a > delta) { sm += a; cm += 1.f; }
    }
    sm = block_reduce_sum(sm);
    cm = block_reduce_sum(cm);
    if (threadIdx.x == 0) alpha[f] = sm / (cm + 1e-8f);

    for (int i = threadIdx.x; i < K; i += blockDim.x) {
        float v = wf[i];
        float a = fabsf(v);
        wtf[i] = (a > delta) ? ((v > 0.f) ? (short)0x3F80 : (short)0xBF80) : (short)0;
    }
}

// ---------------- fp32 -> bf16 cast ----------------
__global__ void f2bf_kernel(const float* __restrict__ in, short* __restrict__ out, int n) {
    int i = blockIdx.x * blockDim.x + threadIdx.x;
    if (i < n) out[i] = f2bs(in[i]);
}

// ---------------- BN stats phase A: vectorized partial sums + atomics ----------------
// grid (C, splits), block 256. Accumulators must be pre-zeroed.
template <typename T, int VEC>
__global__ __launch_bounds__(256) void bn_sum_kernel(
    const T* __restrict__ src, float* __restrict__ sum, float* __restrict__ sq,
    int C, int spatial, int N, int splits) {
    int c = blockIdx.x;
    int vpc = spatial / VEC;          // vectors per (n,c) chunk
    int total = N * vpc;
    float s = 0.f, s2 = 0.f;
    for (int v = blockIdx.y * 256 + threadIdx.x; v < total; v += splits * 256) {
        int n = v / vpc;
        int i = v - n * vpc;
        const T* p = src + ((size_t)n * C + c) * spatial + i * VEC;
        float vals[VEC];
        if (sizeof(T) == 4) {
            // fp32: VEC==4, one float4
            float4 q = *(const float4*)p;
            vals[0] = q.x; vals[1] = q.y; vals[2] = q.z; vals[3] = q.w;
        } else {
            // bf16: VEC==8 (int4) or VEC==4 (int2)
            short tmp[VEC];
            if (VEC == 8) *(int4*)tmp = *(const int4*)p;
            else          *(int2*)tmp = *(const int2*)p;
            #pragma unroll
            for (int k = 0; k < VEC; k++) vals[k] = bs2f(tmp[k]);
        }
        #pragma unroll
        for (int k = 0; k < VEC; k++) { s += vals[k]; s2 += vals[k] * vals[k]; }
    }
    s = block_reduce_sum(s);
    s2 = block_reduce_sum(s2);
    if (threadIdx.x == 0) {
        atomicAdd(&sum[c], s);
        atomicAdd(&sq[c], s2);
    }
}

// ---------------- BN stats phase B: finalize scale/shift ----------------
__global__ void bn_finalize_kernel(const float* __restrict__ sum, const float* __restrict__ sq,
                                   const float* __restrict__ g, const float* __restrict__ b,
                                   float* __restrict__ scale, float* __restrict__ shift,
                                   int C, float cnt) {
    int c = blockIdx.x * blockDim.x + threadIdx.x;
    if (c >= C) return;
    float mean = sum[c] / cnt;
    float var = fmaxf(sq[c] / cnt - mean * mean, 0.f);
    float r = rsqrtf(var + EPS);
    float sc = g[c] * r;
    scale[c] = sc;
    shift[c] = b[c] - mean * sc;
}

// ---------------- affine transpose: in[n][C][SPin] -> Bt[(n*SPout+p)][C] bf16 ----------------
template <typename TIn, bool AFFINE, bool STRIDED>
__global__ __launch_bounds__(256) void affine_transpose_kernel(
    const TIn* __restrict__ in, const float* __restrict__ scale,
    const float* __restrict__ shift, short* __restrict__ Bt,
    int C, int SPin, int SPout, int Wout, int Win) {
    __shared__ short tile[64][65];
    int n = blockIdx.z;
    int ci0 = blockIdx.y * 64;
    int p0 = blockIdx.x * 64;
    int tx = threadIdx.x & 63;
    int ty4 = threadIdx.x >> 6;  // 0..3

    int p = p0 + tx;
    int pin = p;
    if (STRIDED) { int oh = p / Wout, ow = p - oh * Wout; pin = oh * 2 * Win + ow * 2; }
    bool pok = p < SPout;
    const TIn* base = in + ((size_t)n * C + ci0) * SPin;
    #pragma unroll
    for (int r = 0; r < 16; r++) {
        int ci = ty4 + r * 4;
        float v = 0.f;
        if (pok) v = toF(base[(size_t)ci * SPin + pin]);
        if (AFFINE) v = v * scale[ci0 + ci] + shift[ci0 + ci];
        tile[tx][ci] = f2bs(v);
    }
    __syncthreads();
    #pragma unroll
    for (int r = 0; r < 16; r++) {
        int pl = ty4 + r * 4;
        int pw = p0 + pl;
        if (pw < SPout)
            Bt[((size_t)n * SPout + pw) * C + ci0 + tx] = tile[pl][tx];
    }
}

// ---------------- im2col + affine for conv2 (3x3 s2 p1) ----------------
__global__ void im2col_kernel(const bf16* __restrict__ h1,
                              const float* __restrict__ scale, const float* __restrict__ shift,
                              short* __restrict__ B2t, int total) {
    int i = blockIdx.x * blockDim.x + threadIdx.x;
    if (i >= total) return;
    int k = i % 2304;
    int c = i / 2304;
    int ci = k / 9;
    int rr = k - ci * 9;
    int kh = rr / 3, kw = rr - kh * 3;
    int n = c / 196;
    int pp = c - n * 196;
    int oh = pp / 14, ow = pp - oh * 14;
    int ih = 2 * oh - 1 + kh;
    int iw = 2 * ow - 1 + kw;
    float v = 0.f;
    if ((unsigned)ih < 28u && (unsigned)iw < 28u)
        v = toF(h1[((size_t)n * 256 + ci) * 784 + ih * 28 + iw]) * scale[ci] + shift[ci];
    B2t[i] = f2bs(v);
}

// ---------------- MFMA GEMM (128x128 tile, BK=32, 4 waves, 4x4 16x16x32) ----------------
// FUSE: epilogue adds scv*fscale[m]+fshift[m] (residual shortcut) so the final
// elementwise bn_add pass (read sc + read out + write out, ~128 MB) is eliminated.
template <int SP, typename TOut, bool HAS_ALPHA, bool FUSE>
__global__ __launch_bounds__(256) void gemm_kernel(
    const short* __restrict__ A, const short* __restrict__ Bt,
    const float* __restrict__ alpha, TOut* __restrict__ out,
    int M, int K,
    const bf16* __restrict__ scv, const float* __restrict__ fscale,
    const float* __restrict__ fshift) {
    __shared__ short As[128 * 32];
    __shared__ short Bs[128 * 32];
    int t = threadIdx.x;
    int c0 = blockIdx.x * 128;
    int m0 = blockIdx.y * 128;
    int w = t >> 6, l = t & 63;
    int wm = (w >> 1) * 64, wn = (w & 1) * 64;

    int r0 = t >> 2;
    int kg = (t & 3) * 8;

    float4v acc[4][4];
    #pragma unroll
    for (int i = 0; i < 4; i++)
        #pragma unroll
        for (int j = 0; j < 4; j++) acc[i][j] = (float4v)0.f;

    int lm = (l >> 4);
    int lc = l & 15;

    for (int k0 = 0; k0 < K; k0 += 32) {
        int4 av0 = *(const int4*)(A + (size_t)(m0 + r0) * K + k0 + kg);
        int4 av1 = *(const int4*)(A + (size_t)(m0 + r0 + 64) * K + k0 + kg);
        int4 bv0 = *(const int4*)(Bt + (size_t)(c0 + r0) * K + k0 + kg);
        int4 bv1 = *(const int4*)(Bt + (size_t)(c0 + r0 + 64) * K + k0 + kg);
        __syncthreads();
        *(int4*)&As[r0 * 32 + kg] = av0;
        *(int4*)&As[(r0 + 64) * 32 + kg] = av1;
        *(int4*)&Bs[r0 * 32 + kg] = bv0;
        *(int4*)&Bs[(r0 + 64) * 32 + kg] = bv1;
        __syncthreads();

        short8 af[4], bfr[4];
        #pragma unroll
        for (int i = 0; i < 4; i++)
            af[i] = *(const short8*)&As[(wm + i * 16 + lc) * 32 + lm * 8];
        #pragma unroll
        for (int j = 0; j < 4; j++)
            bfr[j] = *(const short8*)&Bs[(wn + j * 16 + lc) * 32 + lm * 8];
        #pragma unroll
        for (int i = 0; i < 4; i++)
            #pragma unroll
            for (int j = 0; j < 4; j++)
                acc[i][j] = __builtin_amdgcn_mfma_f32_16x16x32_bf16(af[i], bfr[j], acc[i][j], 0, 0, 0);
    }

    #pragma unroll
    for (int i = 0; i < 4; i++) {
        #pragma unroll
        for (int r = 0; r < 4; r++) {
            int m = m0 + wm + i * 16 + lm * 4 + r;
            float a = HAS_ALPHA ? alpha[m] : 1.f;
            float fsc = FUSE ? fscale[m] : 0.f;
            float fsh = FUSE ? fshift[m] : 0.f;
            #pragma unroll
            for (int j = 0; j < 4; j++) {
                int c = c0 + wn + j * 16 + lc;
                int n = c / SP;
                int p = c - n * SP;
                size_t idx = ((size_t)n * M + m) * SP + p;
                float v = acc[i][j][r] * a;
                if (FUSE) v += toF(scv[idx]) * fsc + fsh;
                stF(&out[idx], v);
            }
        }
    }
}

extern "C" void kernel_launch(void* const* d_in, const int* in_sizes, int n_in,
                              void* d_out, int out_size, void* d_ws, size_t ws_size,
                              hipStream_t stream) {
    const float* x      = (const float*)d_in[0];   // (64,512,28,28)
    const float* bn1_g  = (const float*)d_in[1];
    const float* bn1_b  = (const float*)d_in[2];
    const float* w1     = (const float*)d_in[3];   // (256,512,1,1)
    const float* bn2_g  = (const float*)d_in[4];
    const float* bn2_b  = (const float*)d_in[5];
    const float* w2     = (const float*)d_in[6];   // (256,256,3,3)
    const float* bn3_g  = (const float*)d_in[7];
    const float* bn3_b  = (const float*)d_in[8];
    const float* w3     = (const float*)d_in[9];   // (1024,256,1,1)
    const float* ds_w   = (const float*)d_in[10];  // (1024,512,1,1) NOT ternarized
    const float* dbn_g  = (const float*)d_in[11];
    const float* dbn_b  = (const float*)d_in[12];
    float* out = (float*)d_out;

    const int N = 64, C1 = 512, C2 = 256, C3 = 1024;
    const int SP1 = 784, SP2 = 196;
    const int NT1 = N * SP1;   // 50176
    const int NT2 = N * SP2;   // 12544

    // ---- workspace layout ----
    char* wsb = (char*)d_ws;
    size_t off = 0;
    auto alloc = [&](size_t bytes) { char* p = wsb + off; off += (bytes + 255) & ~(size_t)255; return p; };

    char* pool = alloc((size_t)NT2 * 2304 * 2);          // 57.8 MB (B1t/B2t/B3t/B4t time-share)
    short* B1t = (short*)pool;                            // 51.4 MB  [0, 51.4M)
    short* B2t = (short*)pool;                            // 57.8 MB  [0, 57.8M)
    short* B3t = (short*)pool;                            //  6.4 MB  [0, 6.4M)
    short* B4t = (short*)(pool + (size_t)8 * 1024 * 1024);   // 12.8 MB [8M, 20.8M) — must not overlap B3t (both live)
    bf16*  sc  = (bf16*)(pool + (size_t)32 * 1024 * 1024);   // 25.7 MB [32M, 57.7M)

    bf16* h1 = (bf16*)alloc((size_t)N * C2 * SP1 * 2);
    bf16* h2 = (bf16*)alloc((size_t)N * C2 * SP2 * 2);
    short* w1t  = (short*)alloc((size_t)C2 * C1 * 2);
    short* w2t  = (short*)alloc((size_t)C2 * C2 * 9 * 2);
    short* w3t  = (short*)alloc((size_t)C3 * C2 * 2);
    short* dswb = (short*)alloc((size_t)C3 * C1 * 2);
    float* alpha1 = (float*)alloc(C2 * 4);
    float* alpha2 = (float*)alloc(C2 * 4);
    float* alpha3 = (float*)alloc(C3 * 4);
    float* scale1 = (float*)alloc(C1 * 4);
    float* shift1 = (float*)alloc(C1 * 4);
    float* scale2 = (float*)alloc(C2 * 4);
    float* shift2 = (float*)alloc(C2 * 4);
    float* scale3 = (float*)alloc(C2 * 4);
    float* shift3 = (float*)alloc(C2 * 4);
    float* scaled = (float*)alloc(C3 * 4);
    float* shiftd = (float*)alloc(C3 * 4);
    // BN accumulators (contiguous so one memset clears all): 512+256+256+1024 channels x2
    float* acc_base = (float*)alloc((size_t)(C1 + C2 + C2 + C3) * 2 * 4);
    float* sum1 = acc_base;            float* sq1 = sum1 + C1;
    float* sum2 = sq1 + C1;            float* sq2 = sum2 + C2;
    float* sum3 = sq2 + C2;            float* sq3 = sum3 + C2;
    float* sumd = sq3 + C2;            float* sqd = sumd + C3;
    (void)ws_size; (void)in_sizes; (void)n_in; (void)out_size;

    // 0) zero BN accumulators (capture-safe async memset)
    hipMemsetAsync(acc_base, 0, (size_t)(C1 + C2 + C2 + C3) * 2 * 4, stream);

    // 1) weights
    ternarize_kernel<<<C2, 256, 0, stream>>>(w1, w1t, alpha1, C1);
    ternarize_kernel<<<C2, 256, 0, stream>>>(w2, w2t, alpha2, C2 * 9);
    ternarize_kernel<<<C3, 256, 0, stream>>>(w3, w3t, alpha3, C2);
    f2bf_kernel<<<(C3 * C1 + 255) / 256, 256, 0, stream>>>(ds_w, dswb, C3 * C1);

    // 2) bn1 stats (fast) + B1t = bn1(x)^T bf16
    bn_sum_kernel<float, 4><<<dim3(C1, 8), 256, 0, stream>>>(x, sum1, sq1, C1, SP1, N, 8);
    bn_finalize_kernel<<<(C1 + 255) / 256, 256, 0, stream>>>(sum1, sq1, bn1_g, bn1_b,
                                                             scale1, shift1, C1, (float)(N * SP1));
    {
        dim3 grid((SP1 + 63) / 64, C1 / 64, N);
        affine_transpose_kernel<float, true, false><<<grid, 256, 0, stream>>>(
            x, scale1, shift1, B1t, C1, SP1, SP1, 0, 0);
    }

    // 3) GEMM1: h1 = alpha1 * (w1t . B1t^T)   M=256 K=512 SP=784
    gemm_kernel<784, bf16, true, false><<<dim3(NT1 / 128, C2 / 128), 256, 0, stream>>>(
        w1t, B1t, alpha1, h1, C2, C1, nullptr, nullptr, nullptr);

    // 4) bn2 stats (fast) + im2col(B2t)
    bn_sum_kernel<bf16, 8><<<dim3(C2, 8), 256, 0, stream>>>(h1, sum2, sq2, C2, SP1, N, 8);
    bn_finalize_kernel<<<(C2 + 255) / 256, 256, 0, stream>>>(sum2, sq2, bn2_g, bn2_b,
                                                             scale2, shift2, C2, (float)(N * SP1));
    {
        int total = NT2 * 2304;
        im2col_kernel<<<(total + 255) / 256, 256, 0, stream>>>(h1, scale2, shift2, B2t, total);
    }

    // 5) GEMM2: h2 = alpha2 * (w2t . B2t^T)   M=256 K=2304 SP=196
    gemm_kernel<196, bf16, true, false><<<dim3(NT2 / 128, C2 / 128), 256, 0, stream>>>(
        w2t, B2t, alpha2, h2, C2, C2 * 9, nullptr, nullptr, nullptr);

    // 6) bn3 stats (fast) + B3t = bn3(h2)^T  (B3t at pool offset 0, 6.4 MB)
    bn_sum_kernel<bf16, 4><<<dim3(C2, 4), 256, 0, stream>>>(h2, sum3, sq3, C2, SP2, N, 4);
    bn_finalize_kernel<<<(C2 + 255) / 256, 256, 0, stream>>>(sum3, sq3, bn3_g, bn3_b,
                                                             scale3, shift3, C2, (float)(N * SP2));
    {
        dim3 grid((SP2 + 63) / 64, C2 / 64, N);
        affine_transpose_kernel<bf16, true, false><<<grid, 256, 0, stream>>>(
            h2, scale3, shift3, B3t, C2, SP2, SP2, 0, 0);
    }

    // 7) shortcut branch FIRST: B4t = x strided s2 (no affine), GEMM4: sc = dswb . B4t^T
    {
        dim3 grid((SP2 + 63) / 64, C1 / 64, N);
        affine_transpose_kernel<float, false, true><<<grid, 256, 0, stream>>>(
            x, nullptr, nullptr, B4t, C1, SP1, SP2, 14, 28);
    }
    gemm_kernel<196, bf16, false, false><<<dim3(NT2 / 128, C3 / 128), 256, 0, stream>>>(
        dswb, B4t, nullptr, sc, C3, C1, nullptr, nullptr, nullptr);

    // 8) ds bn stats on sc
    bn_sum_kernel<bf16, 4><<<dim3(C3, 4), 256, 0, stream>>>(sc, sumd, sqd, C3, SP2, N, 4);
    bn_finalize_kernel<<<(C3 + 255) / 256, 256, 0, stream>>>(sumd, sqd, dbn_g, dbn_b,
                                                             scaled, shiftd, C3, (float)(N * SP2));

    // 9) GEMM3 with fused residual: out = alpha3*(w3t . B3t^T) + sc*scaled + shiftd
    //    M=1024 K=256 SP=196, fp32 out — single write of out, bn_add pass eliminated
    gemm_kernel<196, float, true, true><<<dim3(NT2 / 128, C3 / 128), 256, 0, stream>>>(
        w3t, B3t, alpha3, out, C3, C2, sc, scaled, shiftd);
}

// Round 2
// 482.504 us; speedup vs baseline: 1.0754x; 1.0754x over previous
//
#include <hip/hip_runtime.h>
#include <hip/hip_bf16.h>
#include <math.h>

#define EPS 1e-5f

typedef __hip_bfloat16 bf16;
typedef short short8 __attribute__((ext_vector_type(8)));
typedef float float4v __attribute__((ext_vector_type(4)));

__device__ __forceinline__ float toF(float v) { return v; }
__device__ __forceinline__ float toF(bf16 v) { return __bfloat162float(v); }
__device__ __forceinline__ void stF(float* p, float v) { *p = v; }
__device__ __forceinline__ void stF(bf16* p, float v) { *p = __float2bfloat16(v); }
__device__ __forceinline__ short f2bs(float v) {
    bf16 b = __float2bfloat16(v);
    return *reinterpret_cast<short*>(&b);
}
__device__ __forceinline__ float bs2f(short s) {
    unsigned u = ((unsigned)(unsigned short)s) << 16;
    return __uint_as_float(u);
}

// ---------------- block reduction (blockDim.x == 256) ----------------
__device__ __forceinline__ float block_reduce_sum(float v) {
    __shared__ float s[256];
    int t = threadIdx.x;
    s[t] = v;
    __syncthreads();
    #pragma unroll
    for (int st = 128; st > 0; st >>= 1) {
        if (t < st) s[t] += s[t + st];
        __syncthreads();
    }
    float r = s[0];
    __syncthreads();
    return r;
}

// ---------------- ternarize -> bf16 {-1,0,+1} + fp32 alpha ----------------
__global__ void ternarize_kernel(const float* __restrict__ w, short* __restrict__ wt,
                                 float* __restrict__ alpha, int K) {
    int f = blockIdx.x;
    const float* wf = w + (size_t)f * K;
    short* wtf = wt + (size_t)f * K;

    float s = 0.f;
    for (int i = threadIdx.x; i < K; i += blockDim.x) s += fabsf(wf[i]);
    float total = block_reduce_sum(s);
    float delta = 0.7f * total / (float)K;

    float sm = 0.f, cm = 0.f;
    for (int i = threadIdx.x; i < K; i += blockDim.x) {
        float a = fabsf(wf[i]);
        if (a > delta) { sm += a; cm += 1.f; }
    }
    sm = block_reduce_sum(sm);
    cm = block_reduce_sum(cm);
    if (threadIdx.x == 0) alpha[f] = sm / (cm + 1e-8f);

    for (int i = threadIdx.x; i < K; i += blockDim.x) {
        float v = wf[i];
        float a = fabsf(v);
        wtf[i] = (a > delta) ? ((v > 0.f) ? (short)0x3F80 : (short)0xBF80) : (short)0;
    }
}

// ---------------- fp32 -> bf16 cast ----------------
__global__ void f2bf_kernel(const float* __restrict__ in, short* __restrict__ out, int n) {
    int i = blockIdx.x * blockDim.x + threadIdx.x;
    if (i < n) out[i] = f2bs(in[i]);
}

// ---------------- BN stats phase A: vectorized partial sums + atomics ----------------
// grid (C, splits), block 256. Accumulators must be pre-zeroed.
template <typename T, int VEC>
__global__ __launch_bounds__(256) void bn_sum_kernel(
    const T* __restrict__ src, float* __restrict__ sum, float* __restrict__ sq,
    int C, int spatial, int N, int splits) {
    int c = blockIdx.x;
    int vpc = spatial / VEC;          // vectors per (n,c) chunk
    int total = N * vpc;
    float s = 0.f, s2 = 0.f;
    for (int v = blockIdx.y * 256 + threadIdx.x; v < total; v += splits * 256) {
        int n = v / vpc;
        int i = v - n * vpc;
        const T* p = src + ((size_t)n * C + c) * spatial + i * VEC;
        float vals[VEC];
        if (sizeof(T) == 4) {
            // fp32: VEC==4, one float4
            float4 q = *(const float4*)p;
            vals[0] = q.x; vals[1] = q.y; vals[2] = q.z; vals[3] = q.w;
        } else {
            // bf16: VEC==8 (int4) or VEC==4 (int2)
            short tmp[VEC];
            if (VEC == 8) *(int4*)tmp = *(const int4*)p;
            else          *(int2*)tmp = *(const int2*)p;
            #pragma unroll
            for (int k = 0; k < VEC; k++) vals[k] = bs2f(tmp[k]);
        }
        #pragma unroll
        for (int k = 0; k < VEC; k++) { s += vals[k]; s2 += vals[k] * vals[k]; }
    }
    s = block_reduce_sum(s);
    s2 = block_reduce_sum(s2);
    if (threadIdx.x == 0) {
        atomicAdd(&sum[c], s);
        atomicAdd(&sq[c], s2);
    }
}

// ---------------- BN stats phase B: finalize scale/shift ----------------
__global__ void bn_finalize_kernel(const float* __restrict__ sum, const float* __restrict__ sq,
                                   const float* __restrict__ g, const float* __restrict__ b,
                                   float* __restrict__ scale, float* __restrict__ shift,
                                   int C, float cnt) {
    int c = blockIdx.x * blockDim.x + threadIdx.x;
    if (c >= C) return;
    float mean = sum[c] / cnt;
    float var = fmaxf(sq[c] / cnt - mean * mean, 0.f);
    float r = rsqrtf(var + EPS);
    float sc = g[c] * r;
    scale[c] = sc;
    shift[c] = b[c] - mean * sc;
}

// ---------------- affine transpose: in[n][C][SPin] -> Bt[(n*SPout+p)][C] bf16 ----------------
template <typename TIn, bool AFFINE, bool STRIDED>
__global__ __launch_bounds__(256) void affine_transpose_kernel(
    const TIn* __restrict__ in, const float* __restrict__ scale,
    const float* __restrict__ shift, short* __restrict__ Bt,
    int C, int SPin, int SPout, int Wout, int Win) {
    __shared__ short tile[64][65];
    int n = blockIdx.z;
    int ci0 = blockIdx.y * 64;
    int p0 = blockIdx.x * 64;
    int tx = threadIdx.x & 63;
    int ty4 = threadIdx.x >> 6;  // 0..3

    int p = p0 + tx;
    int pin = p;
    if (STRIDED) { int oh = p / Wout, ow = p - oh * Wout; pin = oh * 2 * Win + ow * 2; }
    bool pok = p < SPout;
    const TIn* base = in + ((size_t)n * C + ci0) * SPin;
    #pragma unroll
    for (int r = 0; r < 16; r++) {
        int ci = ty4 + r * 4;
        float v = 0.f;
        if (pok) v = toF(base[(size_t)ci * SPin + pin]);
        if (AFFINE) v = v * scale[ci0 + ci] + shift[ci0 + ci];
        tile[tx][ci] = f2bs(v);
    }
    __syncthreads();
    #pragma unroll
    for (int r = 0; r < 16; r++) {
        int pl = ty4 + r * 4;
        int pw = p0 + pl;
        if (pw < SPout)
            Bt[((size_t)n * SPout + pw) * C + ci0 + tx] = tile[pl][tx];
    }
}

// ---------------- LDS-tiled im2col + affine for conv2 (3x3 s2 p1) ----------------
// block = (cb, n): stages h1[n][ci0:ci0+16][0:784] into LDS (coalesced int4,
// affine applied ONCE per input element), then emits B2t slab
// [(n*196+p)*2304 + ci0*9 .. +144) as aligned int4 stores (8 shorts/lane).
__global__ __launch_bounds__(256) void im2col_tiled_kernel(
    const bf16* __restrict__ h1, const float* __restrict__ scale,
    const float* __restrict__ shift, short* __restrict__ B2t) {
    __shared__ short tile[16][784];   // 25 KB; row stride 1568 B = 98*16 -> int4 aligned
    int cb = blockIdx.x;              // 0..15 (16-channel slab)
    int n  = blockIdx.y;              // 0..63
    int ci0 = cb * 16;
    int t = threadIdx.x;

    // phase 1: load + affine. 16 ch * 98 int4 = 1568 int4 over 256 threads
    for (int v = t; v < 16 * 98; v += 256) {
        int ci = v / 98;
        int i8 = (v - ci * 98) * 8;
        short tmp[8];
        *(int4*)tmp = *(const int4*)(h1 + ((size_t)n * 256 + ci0 + ci) * 784 + i8);
        float sc = scale[ci0 + ci], sh = shift[ci0 + ci];
        short ov[8];
        #pragma unroll
        for (int k = 0; k < 8; k++) ov[k] = f2bs(bs2f(tmp[k]) * sc + sh);
        *(int4*)&tile[ci][i8] = *(int4*)ov;
    }
    __syncthreads();

    // phase 2: per output pixel p, 16 ci * 9 rr = 144 shorts = 18 int4 segments.
    // 196 p * 18 = 3528 int4 stores over 256 threads.
    for (int w = t; w < 196 * 18; w += 256) {
        int p = w / 18, seg = w - p * 18;
        int oh = p / 14, ow = p - oh * 14;
        int kbase = seg * 8;          // local k within [0,144)
        short vals[8];
        #pragma unroll
        for (int u = 0; u < 8; u++) {
            int kk = kbase + u;       // ci_l*9 + rr
            int ci_l = kk / 9;
            int rr = kk - ci_l * 9;
            int kh = rr / 3, kw = rr - kh * 3;
            int ih = 2 * oh - 1 + kh;
            int iw = 2 * ow - 1 + kw;
            vals[u] = ((unsigned)ih < 28u && (unsigned)iw < 28u)
                          ? tile[ci_l][ih * 28 + iw] : (short)0;
        }
        // byte offset: 2304*c (mult of 8 shorts), ci0*9 = 144*cb, kbase = 8*seg -> int4 aligned
        *(int4*)(B2t + ((size_t)(n * 196 + p)) * 2304 + ci0 * 9 + kbase) = *(int4*)vals;
    }
}

// ---------------- MFMA GEMM (128x128 tile, BK=32, 4 waves, 4x4 16x16x32) ----------------
// FUSE: epilogue adds scv*fscale[m]+fshift[m] (residual shortcut) so the final
// elementwise bn_add pass (read sc + read out + write out, ~128 MB) is eliminated.
template <int SP, typename TOut, bool HAS_ALPHA, bool FUSE>
__global__ __launch_bounds__(256) void gemm_kernel(
    const short* __restrict__ A, const short* __restrict__ Bt,
    const float* __restrict__ alpha, TOut* __restrict__ out,
    int M, int K,
    const bf16* __restrict__ scv, const float* __restrict__ fscale,
    const float* __restrict__ fshift) {
    __shared__ short As[128 * 32];
    __shared__ short Bs[128 * 32];
    int t = threadIdx.x;
    int c0 = blockIdx.x * 128;
    int m0 = blockIdx.y * 128;
    int w = t >> 6, l = t & 63;
    int wm = (w >> 1) * 64, wn = (w & 1) * 64;

    int r0 = t >> 2;
    int kg = (t & 3) * 8;

    float4v acc[4][4];
    #pragma unroll
    for (int i = 0; i < 4; i++)
        #pragma unroll
        for (int j = 0; j < 4; j++) acc[i][j] = (float4v)0.f;

    int lm = (l >> 4);
    int lc = l & 15;

    for (int k0 = 0; k0 < K; k0 += 32) {
        int4 av0 = *(const int4*)(A + (size_t)(m0 + r0) * K + k0 + kg);
        int4 av1 = *(const int4*)(A + (size_t)(m0 + r0 + 64) * K + k0 + kg);
        int4 bv0 = *(const int4*)(Bt + (size_t)(c0 + r0) * K + k0 + kg);
        int4 bv1 = *(const int4*)(Bt + (size_t)(c0 + r0 + 64) * K + k0 + kg);
        __syncthreads();
        *(int4*)&As[r0 * 32 + kg] = av0;
        *(int4*)&As[(r0 + 64) * 32 + kg] = av1;
        *(int4*)&Bs[r0 * 32 + kg] = bv0;
        *(int4*)&Bs[(r0 + 64) * 32 + kg] = bv1;
        __syncthreads();

        short8 af[4], bfr[4];
        #pragma unroll
        for (int i = 0; i < 4; i++)
            af[i] = *(const short8*)&As[(wm + i * 16 + lc) * 32 + lm * 8];
        #pragma unroll
        for (int j = 0; j < 4; j++)
            bfr[j] = *(const short8*)&Bs[(wn + j * 16 + lc) * 32 + lm * 8];
        #pragma unroll
        for (int i = 0; i < 4; i++)
            #pragma unroll
            for (int j = 0; j < 4; j++)
                acc[i][j] = __builtin_amdgcn_mfma_f32_16x16x32_bf16(af[i], bfr[j], acc[i][j], 0, 0, 0);
    }

    #pragma unroll
    for (int i = 0; i < 4; i++) {
        #pragma unroll
        for (int r = 0; r < 4; r++) {
            int m = m0 + wm + i * 16 + lm * 4 + r;
            float a = HAS_ALPHA ? alpha[m] : 1.f;
            float fsc = FUSE ? fscale[m] : 0.f;
            float fsh = FUSE ? fshift[m] : 0.f;
            #pragma unroll
            for (int j = 0; j < 4; j++) {
                int c = c0 + wn + j * 16 + lc;
                int n = c / SP;
                int p = c - n * SP;
                size_t idx = ((size_t)n * M + m) * SP + p;
                float v = acc[i][j][r] * a;
                if (FUSE) v += toF(scv[idx]) * fsc + fsh;
                stF(&out[idx], v);
            }
        }
    }
}

extern "C" void kernel_launch(void* const* d_in, const int* in_sizes, int n_in,
                              void* d_out, int out_size, void* d_ws, size_t ws_size,
                              hipStream_t stream) {
    const float* x      = (const float*)d_in[0];   // (64,512,28,28)
    const float* bn1_g  = (const float*)d_in[1];
    const float* bn1_b  = (const float*)d_in[2];
    const float* w1     = (const float*)d_in[3];   // (256,512,1,1)
    const float* bn2_g  = (const float*)d_in[4];
    const float* bn2_b  = (const float*)d_in[5];
    const float* w2     = (const float*)d_in[6];   // (256,256,3,3)
    const float* bn3_g  = (const float*)d_in[7];
    const float* bn3_b  = (const float*)d_in[8];
    const float* w3     = (const float*)d_in[9];   // (1024,256,1,1)
    const float* ds_w   = (const float*)d_in[10];  // (1024,512,1,1) NOT ternarized
    const float* dbn_g  = (const float*)d_in[11];
    const float* dbn_b  = (const float*)d_in[12];
    float* out = (float*)d_out;

    const int N = 64, C1 = 512, C2 = 256, C3 = 1024;
    const int SP1 = 784, SP2 = 196;
    const int NT1 = N * SP1;   // 50176
    const int NT2 = N * SP2;   // 12544

    // ---- workspace layout ----
    char* wsb = (char*)d_ws;
    size_t off = 0;
    auto alloc = [&](size_t bytes) { char* p = wsb + off; off += (bytes + 255) & ~(size_t)255; return p; };

    char* pool = alloc((size_t)NT2 * 2304 * 2);          // 57.8 MB (B1t/B2t/B3t/B4t time-share)
    short* B1t = (short*)pool;                            // 51.4 MB  [0, 51.4M)
    short* B2t = (short*)pool;                            // 57.8 MB  [0, 57.8M)
    short* B3t = (short*)pool;                            //  6.4 MB  [0, 6.4M)
    short* B4t = (short*)(pool + (size_t)8 * 1024 * 1024);   // 12.8 MB [8M, 20.8M) — must not overlap B3t (both live)
    bf16*  sc  = (bf16*)(pool + (size_t)32 * 1024 * 1024);   // 25.7 MB [32M, 57.7M)

    bf16* h1 = (bf16*)alloc((size_t)N * C2 * SP1 * 2);
    bf16* h2 = (bf16*)alloc((size_t)N * C2 * SP2 * 2);
    short* w1t  = (short*)alloc((size_t)C2 * C1 * 2);
    short* w2t  = (short*)alloc((size_t)C2 * C2 * 9 * 2);
    short* w3t  = (short*)alloc((size_t)C3 * C2 * 2);
    short* dswb = (short*)alloc((size_t)C3 * C1 * 2);
    float* alpha1 = (float*)alloc(C2 * 4);
    float* alpha2 = (float*)alloc(C2 * 4);
    float* alpha3 = (float*)alloc(C3 * 4);
    float* scale1 = (float*)alloc(C1 * 4);
    float* shift1 = (float*)alloc(C1 * 4);
    float* scale2 = (float*)alloc(C2 * 4);
    float* shift2 = (float*)alloc(C2 * 4);
    float* scale3 = (float*)alloc(C2 * 4);
    float* shift3 = (float*)alloc(C2 * 4);
    float* scaled = (float*)alloc(C3 * 4);
    float* shiftd = (float*)alloc(C3 * 4);
    // BN accumulators (contiguous so one memset clears all): 512+256+256+1024 channels x2
    float* acc_base = (float*)alloc((size_t)(C1 + C2 + C2 + C3) * 2 * 4);
    float* sum1 = acc_base;            float* sq1 = sum1 + C1;
    float* sum2 = sq1 + C1;            float* sq2 = sum2 + C2;
    float* sum3 = sq2 + C2;            float* sq3 = sum3 + C2;
    float* sumd = sq3 + C2;            float* sqd = sumd + C3;
    (void)ws_size; (void)in_sizes; (void)n_in; (void)out_size;

    // 0) zero BN accumulators (capture-safe async memset)
    hipMemsetAsync(acc_base, 0, (size_t)(C1 + C2 + C2 + C3) * 2 * 4, stream);

    // 1) weights
    ternarize_kernel<<<C2, 256, 0, stream>>>(w1, w1t, alpha1, C1);
    ternarize_kernel<<<C2, 256, 0, stream>>>(w2, w2t, alpha2, C2 * 9);
    ternarize_kernel<<<C3, 256, 0, stream>>>(w3, w3t, alpha3, C2);
    f2bf_kernel<<<(C3 * C1 + 255) / 256, 256, 0, stream>>>(ds_w, dswb, C3 * C1);

    // 2) bn1 stats (fast) + B1t = bn1(x)^T bf16
    bn_sum_kernel<float, 4><<<dim3(C1, 8), 256, 0, stream>>>(x, sum1, sq1, C1, SP1, N, 8);
    bn_finalize_kernel<<<(C1 + 255) / 256, 256, 0, stream>>>(sum1, sq1, bn1_g, bn1_b,
                                                             scale1, shift1, C1, (float)(N * SP1));
    {
        dim3 grid((SP1 + 63) / 64, C1 / 64, N);
        affine_transpose_kernel<float, true, false><<<grid, 256, 0, stream>>>(
            x, scale1, shift1, B1t, C1, SP1, SP1, 0, 0);
    }

    // 3) GEMM1: h1 = alpha1 * (w1t . B1t^T)   M=256 K=512 SP=784
    gemm_kernel<784, bf16, true, false><<<dim3(NT1 / 128, C2 / 128), 256, 0, stream>>>(
        w1t, B1t, alpha1, h1, C2, C1, nullptr, nullptr, nullptr);

    // 4) bn2 stats (fast) + LDS-tiled im2col(B2t)
    bn_sum_kernel<bf16, 8><<<dim3(C2, 8), 256, 0, stream>>>(h1, sum2, sq2, C2, SP1, N, 8);
    bn_finalize_kernel<<<(C2 + 255) / 256, 256, 0, stream>>>(sum2, sq2, bn2_g, bn2_b,
                                                             scale2, shift2, C2, (float)(N * SP1));
    im2col_tiled_kernel<<<dim3(16, 64), 256, 0, stream>>>(h1, scale2, shift2, B2t);

    // 5) GEMM2: h2 = alpha2 * (w2t . B2t^T)   M=256 K=2304 SP=196
    gemm_kernel<196, bf16, true, false><<<dim3(NT2 / 128, C2 / 128), 256, 0, stream>>>(
        w2t, B2t, alpha2, h2, C2, C2 * 9, nullptr, nullptr, nullptr);

    // 6) bn3 stats (fast) + B3t = bn3(h2)^T  (B3t at pool offset 0, 6.4 MB)
    bn_sum_kernel<bf16, 4><<<dim3(C2, 4), 256, 0, stream>>>(h2, sum3, sq3, C2, SP2, N, 4);
    bn_finalize_kernel<<<(C2 + 255) / 256, 256, 0, stream>>>(sum3, sq3, bn3_g, bn3_b,
                                                             scale3, shift3, C2, (float)(N * SP2));
    {
        dim3 grid((SP2 + 63) / 64, C2 / 64, N);
        affine_transpose_kernel<bf16, true, false><<<grid, 256, 0, stream>>>(
            h2, scale3, shift3, B3t, C2, SP2, SP2, 0, 0);
    }

    // 7) shortcut branch FIRST: B4t = x strided s2 (no affine), GEMM4: sc = dswb . B4t^T
    {
        dim3 grid((SP2 + 63) / 64, C1 / 64, N);
        affine_transpose_kernel<float, false, true><<<grid, 256, 0, stream>>>(
            x, nullptr, nullptr, B4t, C1, SP1, SP2, 14, 28);
    }
    gemm_kernel<196, bf16, false, false><<<dim3(NT2 / 128, C3 / 128), 256, 0, stream>>>(
        dswb, B4t, nullptr, sc, C3, C1, nullptr, nullptr, nullptr);

    // 8) ds bn stats on sc
    bn_sum_kernel<bf16, 4><<<dim3(C3, 4), 256, 0, stream>>>(sc, sumd, sqd, C3, SP2, N, 4);
    bn_finalize_kernel<<<(C3 + 255) / 256, 256, 0, stream>>>(sumd, sqd, dbn_g, dbn_b,
                                                             scaled, shiftd, C3, (float)(N * SP2));

    // 9) GEMM3 with fused residual: out = alpha3*(w3t . B3t^T) + sc*scaled + shiftd
    //    M=1024 K=256 SP=196, fp32 out — single write of out, bn_add pass eliminated
    gemm_kernel<196, float, true, true><<<dim3(NT2 / 128, C3 / 128), 256, 0, stream>>>(
        w3t, B3t, alpha3, out, C3, C2, sc, scaled, shiftd);
}

// Round 3
// 465.391 us; speedup vs baseline: 1.1149x; 1.0368x over previous
//
#include <hip/hip_runtime.h>
#include <hip/hip_bf16.h>
#include <math.h>

#define EPS 1e-5f

typedef __hip_bfloat16 bf16;
typedef short short8 __attribute__((ext_vector_type(8)));
typedef float float4v __attribute__((ext_vector_type(4)));

__device__ __forceinline__ float toF(float v) { return v; }
__device__ __forceinline__ float toF(bf16 v) { return __bfloat162float(v); }
__device__ __forceinline__ void stF(float* p, float v) { *p = v; }
__device__ __forceinline__ void stF(bf16* p, float v) { *p = __float2bfloat16(v); }
__device__ __forceinline__ short f2bs(float v) {
    bf16 b = __float2bfloat16(v);
    return *reinterpret_cast<short*>(&b);
}
__device__ __forceinline__ float bs2f(short s) {
    unsigned u = ((unsigned)(unsigned short)s) << 16;
    return __uint_as_float(u);
}

// ---------------- block reduction (blockDim.x == 256) ----------------
__device__ __forceinline__ float block_reduce_sum(float v) {
    __shared__ float s[256];
    int t = threadIdx.x;
    s[t] = v;
    __syncthreads();
    #pragma unroll
    for (int st = 128; st > 0; st >>= 1) {
        if (t < st) s[t] += s[t + st];
        __syncthreads();
    }
    float r = s[0];
    __syncthreads();
    return r;
}

// ---------------- ternarize -> bf16 {-1,0,+1} + fp32 alpha ----------------
__global__ void ternarize_kernel(const float* __restrict__ w, short* __restrict__ wt,
                                 float* __restrict__ alpha, int K) {
    int f = blockIdx.x;
    const float* wf = w + (size_t)f * K;
    short* wtf = wt + (size_t)f * K;

    float s = 0.f;
    for (int i = threadIdx.x; i < K; i += blockDim.x) s += fabsf(wf[i]);
    float total = block_reduce_sum(s);
    float delta = 0.7f * total / (float)K;

    float sm = 0.f, cm = 0.f;
    for (int i = threadIdx.x; i < K; i += blockDim.x) {
        float a = fabsf(wf[i]);
        if (a > delta) { sm += a; cm += 1.f; }
    }
    sm = block_reduce_sum(sm);
    cm = block_reduce_sum(cm);
    if (threadIdx.x == 0) alpha[f] = sm / (cm + 1e-8f);

    for (int i = threadIdx.x; i < K; i += blockDim.x) {
        float v = wf[i];
        float a = fabsf(v);
        wtf[i] = (a > delta) ? ((v > 0.f) ? (short)0x3F80 : (short)0xBF80) : (short)0;
    }
}

// ---------------- fold bn1 scale into w1t + compute bias1 = w1t . shift1 ----------------
__global__ void foldbias_kernel(const short* __restrict__ wt, const float* __restrict__ scale,
                                const float* __restrict__ shift, short* __restrict__ wf,
                                float* __restrict__ bias, int K) {
    int f = blockIdx.x;
    float s = 0.f;
    for (int k = threadIdx.x; k < K; k += blockDim.x) {
        float tv = bs2f(wt[(size_t)f * K + k]);
        wf[(size_t)f * K + k] = f2bs(tv * scale[k]);
        s += tv * shift[k];
    }
    s = block_reduce_sum(s);
    if (threadIdx.x == 0) bias[f] = s;
}

// ---------------- fp32 -> bf16 cast ----------------
__global__ void f2bf_kernel(const float* __restrict__ in, short* __restrict__ out, int n) {
    int i = blockIdx.x * blockDim.x + threadIdx.x;
    if (i < n) out[i] = f2bs(in[i]);
}

// ---------------- BN stats phase A: vectorized partial sums + atomics ----------------
// grid (C, splits), block 256. Accumulators must be pre-zeroed.
template <typename T, int VEC>
__global__ __launch_bounds__(256) void bn_sum_kernel(
    const T* __restrict__ src, float* __restrict__ sum, float* __restrict__ sq,
    int C, int spatial, int N, int splits) {
    int c = blockIdx.x;
    int vpc = spatial / VEC;          // vectors per (n,c) chunk
    int total = N * vpc;
    float s = 0.f, s2 = 0.f;
    for (int v = blockIdx.y * 256 + threadIdx.x; v < total; v += splits * 256) {
        int n = v / vpc;
        int i = v - n * vpc;
        const T* p = src + ((size_t)n * C + c) * spatial + i * VEC;
        float vals[VEC];
        if (sizeof(T) == 4) {
            float4 q = *(const float4*)p;
            vals[0] = q.x; vals[1] = q.y; vals[2] = q.z; vals[3] = q.w;
        } else {
            short tmp[VEC];
            if (VEC == 8) *(int4*)tmp = *(const int4*)p;
            else          *(int2*)tmp = *(const int2*)p;
            #pragma unroll
            for (int k = 0; k < VEC; k++) vals[k] = bs2f(tmp[k]);
        }
        #pragma unroll
        for (int k = 0; k < VEC; k++) { s += vals[k]; s2 += vals[k] * vals[k]; }
    }
    s = block_reduce_sum(s);
    s2 = block_reduce_sum(s2);
    if (threadIdx.x == 0) {
        atomicAdd(&sum[c], s);
        atomicAdd(&sq[c], s2);
    }
}

// ---------------- BN stats phase B: finalize scale/shift ----------------
__global__ void bn_finalize_kernel(const float* __restrict__ sum, const float* __restrict__ sq,
                                   const float* __restrict__ g, const float* __restrict__ b,
                                   float* __restrict__ scale, float* __restrict__ shift,
                                   int C, float cnt) {
    int c = blockIdx.x * blockDim.x + threadIdx.x;
    if (c >= C) return;
    float mean = sum[c] / cnt;
    float var = fmaxf(sq[c] / cnt - mean * mean, 0.f);
    float r = rsqrtf(var + EPS);
    float sc = g[c] * r;
    scale[c] = sc;
    shift[c] = b[c] - mean * sc;
}

// ---------------- fused stats + raw transpose: x[n][C][SP] -> Bt[(n*SP+p)][C] bf16
// Also accumulates per-channel sum/sumsq (on bf16-rounded values; error ~1e-4 rel, negligible).
__global__ __launch_bounds__(256) void stats_transpose_kernel(
    const float* __restrict__ in, short* __restrict__ Bt,
    float* __restrict__ sum, float* __restrict__ sq, int C, int SP) {
    __shared__ short tile[64][65];
    __shared__ float rs[4][64], rq[4][64];
    int n = blockIdx.z;
    int ci0 = blockIdx.y * 64;
    int p0 = blockIdx.x * 64;
    int tx = threadIdx.x & 63;
    int ty4 = threadIdx.x >> 6;  // 0..3

    int p = p0 + tx;
    bool pok = p < SP;
    const float* base = in + ((size_t)n * C + ci0) * SP;
    #pragma unroll
    for (int r = 0; r < 16; r++) {
        int ci = ty4 + r * 4;
        float v = pok ? base[(size_t)ci * SP + p] : 0.f;
        tile[tx][ci] = f2bs(v);
    }
    __syncthreads();
    float s = 0.f, s2 = 0.f;
    #pragma unroll
    for (int r = 0; r < 16; r++) {
        int pl = ty4 + r * 4;
        int pw = p0 + pl;
        if (pw < SP) {
            short sv = tile[pl][tx];
            Bt[((size_t)n * SP + pw) * C + ci0 + tx] = sv;
            float v = bs2f(sv);
            s += v; s2 += v * v;
        }
    }
    rs[ty4][tx] = s; rq[ty4][tx] = s2;
    __syncthreads();
    if (ty4 == 0) {
        float ts = rs[0][tx] + rs[1][tx] + rs[2][tx] + rs[3][tx];
        float tq = rq[0][tx] + rq[1][tx] + rq[2][tx] + rq[3][tx];
        atomicAdd(&sum[ci0 + tx], ts);
        atomicAdd(&sq[ci0 + tx], tq);
    }
}

// ---------------- affine transpose: in[n][C][SPin] -> Bt[(n*SPout+p)][C] bf16 ----------------
template <typename TIn, bool AFFINE>
__global__ __launch_bounds__(256) void affine_transpose_kernel(
    const TIn* __restrict__ in, const float* __restrict__ scale,
    const float* __restrict__ shift, short* __restrict__ Bt,
    int C, int SPin, int SPout) {
    __shared__ short tile[64][65];
    int n = blockIdx.z;
    int ci0 = blockIdx.y * 64;
    int p0 = blockIdx.x * 64;
    int tx = threadIdx.x & 63;
    int ty4 = threadIdx.x >> 6;  // 0..3

    int p = p0 + tx;
    bool pok = p < SPout;
    const TIn* base = in + ((size_t)n * C + ci0) * SPin;
    #pragma unroll
    for (int r = 0; r < 16; r++) {
        int ci = ty4 + r * 4;
        float v = 0.f;
        if (pok) v = toF(base[(size_t)ci * SPin + p]);
        if (AFFINE) v = v * scale[ci0 + ci] + shift[ci0 + ci];
        tile[tx][ci] = f2bs(v);
    }
    __syncthreads();
    #pragma unroll
    for (int r = 0; r < 16; r++) {
        int pl = ty4 + r * 4;
        int pw = p0 + pl;
        if (pw < SPout)
            Bt[((size_t)n * SPout + pw) * C + ci0 + tx] = tile[pl][tx];
    }
}

// ---------------- LDS-tiled im2col + affine for conv2 (3x3 s2 p1) ----------------
__global__ __launch_bounds__(256) void im2col_tiled_kernel(
    const bf16* __restrict__ h1, const float* __restrict__ scale,
    const float* __restrict__ shift, short* __restrict__ B2t) {
    __shared__ short tile[16][784];   // 25 KB
    int cb = blockIdx.x;              // 0..15 (16-channel slab)
    int n  = blockIdx.y;              // 0..63
    int ci0 = cb * 16;
    int t = threadIdx.x;

    for (int v = t; v < 16 * 98; v += 256) {
        int ci = v / 98;
        int i8 = (v - ci * 98) * 8;
        short tmp[8];
        *(int4*)tmp = *(const int4*)(h1 + ((size_t)n * 256 + ci0 + ci) * 784 + i8);
        float sc = scale[ci0 + ci], sh = shift[ci0 + ci];
        short ov[8];
        #pragma unroll
        for (int k = 0; k < 8; k++) ov[k] = f2bs(bs2f(tmp[k]) * sc + sh);
        *(int4*)&tile[ci][i8] = *(int4*)ov;
    }
    __syncthreads();

    for (int w = t; w < 196 * 18; w += 256) {
        int p = w / 18, seg = w - p * 18;
        int oh = p / 14, ow = p - oh * 14;
        int kbase = seg * 8;
        short vals[8];
        #pragma unroll
        for (int u = 0; u < 8; u++) {
            int kk = kbase + u;
            int ci_l = kk / 9;
            int rr = kk - ci_l * 9;
            int kh = rr / 3, kw = rr - kh * 3;
            int ih = 2 * oh - 1 + kh;
            int iw = 2 * ow - 1 + kw;
            vals[u] = ((unsigned)ih < 28u && (unsigned)iw < 28u)
                          ? tile[ci_l][ih * 28 + iw] : (short)0;
        }
        *(int4*)(B2t + ((size_t)(n * 196 + p)) * 2304 + ci0 * 9 + kbase) = *(int4*)vals;
    }
}

// ---------------- MFMA GEMM (128x128 tile, BK=32, 4 waves, 4x4 16x16x32) ----------------
// FUSE: epilogue adds scv*fscale[m]+fshift[m] (fused residual shortcut).
// HAS_BIAS: out = alpha*(acc + bias[m])  (folded-BN bias for GEMM1).
// BREMAP: B row index = stride-2 subsample of a 28x28 grid (GEMM4 reads raw B1t).
template <int SP, typename TOut, bool HAS_ALPHA, bool FUSE, bool HAS_BIAS, bool BREMAP>
__global__ __launch_bounds__(256) void gemm_kernel(
    const short* __restrict__ A, const short* __restrict__ Bt,
    const float* __restrict__ alpha, TOut* __restrict__ out,
    int M, int K,
    const bf16* __restrict__ scv, const float* __restrict__ fscale,
    const float* __restrict__ fshift, const float* __restrict__ bias) {
    __shared__ short As[128 * 32];
    __shared__ short Bs[128 * 32];
    int t = threadIdx.x;
    int c0 = blockIdx.x * 128;
    int m0 = blockIdx.y * 128;
    int w = t >> 6, l = t & 63;
    int wm = (w >> 1) * 64, wn = (w & 1) * 64;

    int r0 = t >> 2;
    int kg = (t & 3) * 8;

    // B row remap (hoisted: independent of k)
    size_t rowB0, rowB1;
    if (BREMAP) {
        int c = c0 + r0;
        int nn = c / 196, pp = c - nn * 196;
        int oh = pp / 14, ow = pp - oh * 14;
        rowB0 = (size_t)nn * 784 + oh * 56 + ow * 2;
        c += 64;
        nn = c / 196; pp = c - nn * 196;
        oh = pp / 14; ow = pp - oh * 14;
        rowB1 = (size_t)nn * 784 + oh * 56 + ow * 2;
    } else {
        rowB0 = c0 + r0;
        rowB1 = c0 + r0 + 64;
    }

    float4v acc[4][4];
    #pragma unroll
    for (int i = 0; i < 4; i++)
        #pragma unroll
        for (int j = 0; j < 4; j++) acc[i][j] = (float4v)0.f;

    int lm = (l >> 4);
    int lc = l & 15;

    for (int k0 = 0; k0 < K; k0 += 32) {
        int4 av0 = *(const int4*)(A + (size_t)(m0 + r0) * K + k0 + kg);
        int4 av1 = *(const int4*)(A + (size_t)(m0 + r0 + 64) * K + k0 + kg);
        int4 bv0 = *(const int4*)(Bt + rowB0 * K + k0 + kg);
        int4 bv1 = *(const int4*)(Bt + rowB1 * K + k0 + kg);
        __syncthreads();
        *(int4*)&As[r0 * 32 + kg] = av0;
        *(int4*)&As[(r0 + 64) * 32 + kg] = av1;
        *(int4*)&Bs[r0 * 32 + kg] = bv0;
        *(int4*)&Bs[(r0 + 64) * 32 + kg] = bv1;
        __syncthreads();

        short8 af[4], bfr[4];
        #pragma unroll
        for (int i = 0; i < 4; i++)
            af[i] = *(const short8*)&As[(wm + i * 16 + lc) * 32 + lm * 8];
        #pragma unroll
        for (int j = 0; j < 4; j++)
            bfr[j] = *(const short8*)&Bs[(wn + j * 16 + lc) * 32 + lm * 8];
        #pragma unroll
        for (int i = 0; i < 4; i++)
            #pragma unroll
            for (int j = 0; j < 4; j++)
                acc[i][j] = __builtin_amdgcn_mfma_f32_16x16x32_bf16(af[i], bfr[j], acc[i][j], 0, 0, 0);
    }

    #pragma unroll
    for (int i = 0; i < 4; i++) {
        #pragma unroll
        for (int r = 0; r < 4; r++) {
            int m = m0 + wm + i * 16 + lm * 4 + r;
            float a = HAS_ALPHA ? alpha[m] : 1.f;
            float bia = HAS_BIAS ? bias[m] : 0.f;
            float fsc = FUSE ? fscale[m] : 0.f;
            float fsh = FUSE ? fshift[m] : 0.f;
            #pragma unroll
            for (int j = 0; j < 4; j++) {
                int c = c0 + wn + j * 16 + lc;
                int n = c / SP;
                int p = c - n * SP;
                size_t idx = ((size_t)n * M + m) * SP + p;
                float v = acc[i][j][r];
                if (HAS_BIAS) v += bia;
                if (HAS_ALPHA) v *= a;
                if (FUSE) v += toF(scv[idx]) * fsc + fsh;
                stF(&out[idx], v);
            }
        }
    }
}

extern "C" void kernel_launch(void* const* d_in, const int* in_sizes, int n_in,
                              void* d_out, int out_size, void* d_ws, size_t ws_size,
                              hipStream_t stream) {
    const float* x      = (const float*)d_in[0];   // (64,512,28,28)
    const float* bn1_g  = (const float*)d_in[1];
    const float* bn1_b  = (const float*)d_in[2];
    const float* w1     = (const float*)d_in[3];   // (256,512,1,1)
    const float* bn2_g  = (const float*)d_in[4];
    const float* bn2_b  = (const float*)d_in[5];
    const float* w2     = (const float*)d_in[6];   // (256,256,3,3)
    const float* bn3_g  = (const float*)d_in[7];
    const float* bn3_b  = (const float*)d_in[8];
    const float* w3     = (const float*)d_in[9];   // (1024,256,1,1)
    const float* ds_w   = (const float*)d_in[10];  // (1024,512,1,1) NOT ternarized
    const float* dbn_g  = (const float*)d_in[11];
    const float* dbn_b  = (const float*)d_in[12];
    float* out = (float*)d_out;

    const int N = 64, C1 = 512, C2 = 256, C3 = 1024;
    const int SP1 = 784, SP2 = 196;
    const int NT1 = N * SP1;   // 50176
    const int NT2 = N * SP2;   // 12544

    // ---- workspace layout ----
    char* wsb = (char*)d_ws;
    size_t off = 0;
    auto alloc = [&](size_t bytes) { char* p = wsb + off; off += (bytes + 255) & ~(size_t)255; return p; };

    char* pool = alloc((size_t)NT2 * 2304 * 2);   // 57.8 MB: B1t (51.4) / B2t (57.8) / B3t (6.4) time-share
    short* B1t = (short*)pool;                    // raw bf16(x)^T; live until GEMM4
    short* B2t = (short*)pool;                    // created by im2col AFTER GEMM4
    short* B3t = (short*)pool;                    // created after B2t is dead
    bf16*  sc  = (bf16*)alloc((size_t)N * C3 * SP2 * 2);  // 25.7 MB, own region (lives across im2col)

    bf16* h1 = (bf16*)alloc((size_t)N * C2 * SP1 * 2);
    bf16* h2 = (bf16*)alloc((size_t)N * C2 * SP2 * 2);
    short* w1t  = (short*)alloc((size_t)C2 * C1 * 2);
    short* w1f  = (short*)alloc((size_t)C2 * C1 * 2);   // scale-folded w1
    short* w2t  = (short*)alloc((size_t)C2 * C2 * 9 * 2);
    short* w3t  = (short*)alloc((size_t)C3 * C2 * 2);
    short* dswb = (short*)alloc((size_t)C3 * C1 * 2);
    float* alpha1 = (float*)alloc(C2 * 4);
    float* alpha2 = (float*)alloc(C2 * 4);
    float* alpha3 = (float*)alloc(C3 * 4);
    float* bias1  = (float*)alloc(C2 * 4);
    float* scale1 = (float*)alloc(C1 * 4);
    float* shift1 = (float*)alloc(C1 * 4);
    float* scale2 = (float*)alloc(C2 * 4);
    float* shift2 = (float*)alloc(C2 * 4);
    float* scale3 = (float*)alloc(C2 * 4);
    float* shift3 = (float*)alloc(C2 * 4);
    float* scaled = (float*)alloc(C3 * 4);
    float* shiftd = (float*)alloc(C3 * 4);
    float* acc_base = (float*)alloc((size_t)(C1 + C2 + C2 + C3) * 2 * 4);
    float* sum1 = acc_base;            float* sq1 = sum1 + C1;
    float* sum2 = sq1 + C1;            float* sq2 = sum2 + C2;
    float* sum3 = sq2 + C2;            float* sq3 = sum3 + C2;
    float* sumd = sq3 + C2;            float* sqd = sumd + C3;
    (void)ws_size; (void)in_sizes; (void)n_in; (void)out_size;

    // 0) zero BN accumulators
    hipMemsetAsync(acc_base, 0, (size_t)(C1 + C2 + C2 + C3) * 2 * 4, stream);

    // 1) weights
    ternarize_kernel<<<C2, 256, 0, stream>>>(w1, w1t, alpha1, C1);
    ternarize_kernel<<<C2, 256, 0, stream>>>(w2, w2t, alpha2, C2 * 9);
    ternarize_kernel<<<C3, 256, 0, stream>>>(w3, w3t, alpha3, C2);
    f2bf_kernel<<<(C3 * C1 + 255) / 256, 256, 0, stream>>>(ds_w, dswb, C3 * C1);

    // 2) single pass over x: B1t = raw bf16(x)^T + bn1 stats; then finalize + fold into w1
    {
        dim3 grid((SP1 + 63) / 64, C1 / 64, N);
        stats_transpose_kernel<<<grid, 256, 0, stream>>>(x, B1t, sum1, sq1, C1, SP1);
    }
    bn_finalize_kernel<<<(C1 + 255) / 256, 256, 0, stream>>>(sum1, sq1, bn1_g, bn1_b,
                                                             scale1, shift1, C1, (float)(N * SP1));
    foldbias_kernel<<<C2, 256, 0, stream>>>(w1t, scale1, shift1, w1f, bias1, C1);

    // 3) GEMM1: h1 = alpha1 * (w1f . B1t^T + bias1)   M=256 K=512 SP=784
    gemm_kernel<784, bf16, true, false, true, false><<<dim3(NT1 / 128, C2 / 128), 256, 0, stream>>>(
        w1f, B1t, alpha1, h1, C2, C1, nullptr, nullptr, nullptr, bias1);

    // 4) shortcut GEMM4 straight from raw B1t (stride-2 row remap): sc = dswb . B1t_s2^T
    //    M=1024 K=512 SP=196 — must run BEFORE im2col overwrites the pool
    gemm_kernel<196, bf16, false, false, false, true><<<dim3(NT2 / 128, C3 / 128), 256, 0, stream>>>(
        dswb, B1t, nullptr, sc, C3, C1, nullptr, nullptr, nullptr, nullptr);

    // 5) ds bn stats on sc
    bn_sum_kernel<bf16, 4><<<dim3(C3, 4), 256, 0, stream>>>(sc, sumd, sqd, C3, SP2, N, 4);
    bn_finalize_kernel<<<(C3 + 255) / 256, 256, 0, stream>>>(sumd, sqd, dbn_g, dbn_b,
                                                             scaled, shiftd, C3, (float)(N * SP2));

    // 6) bn2 stats + LDS-tiled im2col (B2t overwrites pool — B1t dead now)
    bn_sum_kernel<bf16, 8><<<dim3(C2, 8), 256, 0, stream>>>(h1, sum2, sq2, C2, SP1, N, 8);
    bn_finalize_kernel<<<(C2 + 255) / 256, 256, 0, stream>>>(sum2, sq2, bn2_g, bn2_b,
                                                             scale2, shift2, C2, (float)(N * SP1));
    im2col_tiled_kernel<<<dim3(16, 64), 256, 0, stream>>>(h1, scale2, shift2, B2t);

    // 7) GEMM2: h2 = alpha2 * (w2t . B2t^T)   M=256 K=2304 SP=196
    gemm_kernel<196, bf16, true, false, false, false><<<dim3(NT2 / 128, C2 / 128), 256, 0, stream>>>(
        w2t, B2t, alpha2, h2, C2, C2 * 9, nullptr, nullptr, nullptr, nullptr);

    // 8) bn3 stats + B3t = bn3(h2)^T
    bn_sum_kernel<bf16, 4><<<dim3(C2, 4), 256, 0, stream>>>(h2, sum3, sq3, C2, SP2, N, 4);
    bn_finalize_kernel<<<(C2 + 255) / 256, 256, 0, stream>>>(sum3, sq3, bn3_g, bn3_b,
                                                             scale3, shift3, C2, (float)(N * SP2));
    {
        dim3 grid((SP2 + 63) / 64, C2 / 64, N);
        affine_transpose_kernel<bf16, true><<<grid, 256, 0, stream>>>(
            h2, scale3, shift3, B3t, C2, SP2, SP2);
    }

    // 9) GEMM3 with fused residual: out = alpha3*(w3t . B3t^T) + sc*scaled + shiftd
    gemm_kernel<196, float, true, true, false, false><<<dim3(NT2 / 128, C3 / 128), 256, 0, stream>>>(
        w3t, B3t, alpha3, out, C3, C2, sc, scaled, shiftd, nullptr);
}

// Round 4
// 441.763 us; speedup vs baseline: 1.1746x; 1.0535x over previous
//
#include <hip/hip_runtime.h>
#include <hip/hip_bf16.h>
#include <math.h>

#define EPS 1e-5f

typedef __hip_bfloat16 bf16;
typedef short short8 __attribute__((ext_vector_type(8)));
typedef float float4v __attribute__((ext_vector_type(4)));

__device__ __forceinline__ float toF(float v) { return v; }
__device__ __forceinline__ float toF(bf16 v) { return __bfloat162float(v); }
__device__ __forceinline__ void stF(float* p, float v) { *p = v; }
__device__ __forceinline__ void stF(bf16* p, float v) { *p = __float2bfloat16(v); }
__device__ __forceinline__ short f2bs(float v) {
    bf16 b = __float2bfloat16(v);
    return *reinterpret_cast<short*>(&b);
}
__device__ __forceinline__ float bs2f(short s) {
    unsigned u = ((unsigned)(unsigned short)s) << 16;
    return __uint_as_float(u);
}

// ---------------- block reduction (blockDim.x == 256) ----------------
__device__ __forceinline__ float block_reduce_sum(float v) {
    __shared__ float s[256];
    int t = threadIdx.x;
    s[t] = v;
    __syncthreads();
    #pragma unroll
    for (int st = 128; st > 0; st >>= 1) {
        if (t < st) s[t] += s[t + st];
        __syncthreads();
    }
    float r = s[0];
    __syncthreads();
    return r;
}

// ---------------- ternarize -> bf16 {-1,0,+1} + fp32 alpha ----------------
__global__ void ternarize_kernel(const float* __restrict__ w, short* __restrict__ wt,
                                 float* __restrict__ alpha, int K) {
    int f = blockIdx.x;
    const float* wf = w + (size_t)f * K;
    short* wtf = wt + (size_t)f * K;

    float s = 0.f;
    for (int i = threadIdx.x; i < K; i += blockDim.x) s += fabsf(wf[i]);
    float total = block_reduce_sum(s);
    float delta = 0.7f * total / (float)K;

    float sm = 0.f, cm = 0.f;
    for (int i = threadIdx.x; i < K; i += blockDim.x) {
        float a = fabsf(wf[i]);
        if (a > delta) { sm += a; cm += 1.f; }
    }
    sm = block_reduce_sum(sm);
    cm = block_reduce_sum(cm);
    if (threadIdx.x == 0) alpha[f] = sm / (cm + 1e-8f);

    for (int i = threadIdx.x; i < K; i += blockDim.x) {
        float v = wf[i];
        float a = fabsf(v);
        wtf[i] = (a > delta) ? ((v > 0.f) ? (short)0x3F80 : (short)0xBF80) : (short)0;
    }
}

// ---------------- fold bn1 scale into w1t + compute bias1 = w1t . shift1 ----------------
__global__ void foldbias_kernel(const short* __restrict__ wt, const float* __restrict__ scale,
                                const float* __restrict__ shift, short* __restrict__ wf,
                                float* __restrict__ bias, int K) {
    int f = blockIdx.x;
    float s = 0.f;
    for (int k = threadIdx.x; k < K; k += blockDim.x) {
        float tv = bs2f(wt[(size_t)f * K + k]);
        wf[(size_t)f * K + k] = f2bs(tv * scale[k]);
        s += tv * shift[k];
    }
    s = block_reduce_sum(s);
    if (threadIdx.x == 0) bias[f] = s;
}

// ---------------- fp32 -> bf16 cast ----------------
__global__ void f2bf_kernel(const float* __restrict__ in, short* __restrict__ out, int n) {
    int i = blockIdx.x * blockDim.x + threadIdx.x;
    if (i < n) out[i] = f2bs(in[i]);
}

// ---------------- BN stats phase A: vectorized partial sums + atomics ----------------
template <typename T, int VEC>
__global__ __launch_bounds__(256) void bn_sum_kernel(
    const T* __restrict__ src, float* __restrict__ sum, float* __restrict__ sq,
    int C, int spatial, int N, int splits) {
    int c = blockIdx.x;
    int vpc = spatial / VEC;          // vectors per (n,c) chunk
    int total = N * vpc;
    float s = 0.f, s2 = 0.f;
    for (int v = blockIdx.y * 256 + threadIdx.x; v < total; v += splits * 256) {
        int n = v / vpc;
        int i = v - n * vpc;
        const T* p = src + ((size_t)n * C + c) * spatial + i * VEC;
        float vals[VEC];
        if (sizeof(T) == 4) {
            float4 q = *(const float4*)p;
            vals[0] = q.x; vals[1] = q.y; vals[2] = q.z; vals[3] = q.w;
        } else {
            short tmp[VEC];
            if (VEC == 8) *(int4*)tmp = *(const int4*)p;
            else          *(int2*)tmp = *(const int2*)p;
            #pragma unroll
            for (int k = 0; k < VEC; k++) vals[k] = bs2f(tmp[k]);
        }
        #pragma unroll
        for (int k = 0; k < VEC; k++) { s += vals[k]; s2 += vals[k] * vals[k]; }
    }
    s = block_reduce_sum(s);
    s2 = block_reduce_sum(s2);
    if (threadIdx.x == 0) {
        atomicAdd(&sum[c], s);
        atomicAdd(&sq[c], s2);
    }
}

// ---------------- BN stats phase B: finalize scale/shift ----------------
__global__ void bn_finalize_kernel(const float* __restrict__ sum, const float* __restrict__ sq,
                                   const float* __restrict__ g, const float* __restrict__ b,
                                   float* __restrict__ scale, float* __restrict__ shift,
                                   int C, float cnt) {
    int c = blockIdx.x * blockDim.x + threadIdx.x;
    if (c >= C) return;
    float mean = sum[c] / cnt;
    float var = fmaxf(sq[c] / cnt - mean * mean, 0.f);
    float r = rsqrtf(var + EPS);
    float sc = g[c] * r;
    scale[c] = sc;
    shift[c] = b[c] - mean * sc;
}

// ---------------- fused stats + raw transpose (VMEM-wide version) ----------------
// x[n][C][SP] fp32 -> Bt[(n*SP+p)][C] bf16, + per-channel sum/sumsq.
// Phase 1: float4 loads (4 instrs/thread), scattered 2B LDS writes (pad 66 -> ~2-way).
// Phase 2a: int4 stores (2 instrs/thread). Phase 2b: stats from LDS (numerics identical).
__global__ __launch_bounds__(256) void stats_transpose_kernel(
    const float* __restrict__ in, short* __restrict__ Bt,
    float* __restrict__ sum, float* __restrict__ sq, int C, int SP) {
    __shared__ short tile[64][66];
    __shared__ float rs[4][64], rq[4][64];
    int n = blockIdx.z;
    int ci0 = blockIdx.y * 64;
    int p0 = blockIdx.x * 64;
    int t = threadIdx.x;
    int tx = t & 63;
    int ty4 = t >> 6;  // 0..3

    // phase 1: lanes 0..15 along p (4 rows per instr, 256B each)
    {
        int p4 = t & 15;
        int cib = t >> 4;
        int p = p0 + p4 * 4;
        bool pok = (p + 3) < SP;          // SP%4==0 -> all-or-none per float4
        #pragma unroll
        for (int it = 0; it < 4; it++) {
            int ci = cib + it * 16;
            float4 q;
            if (pok) q = *(const float4*)(in + ((size_t)n * C + ci0 + ci) * SP + p);
            else     q = make_float4(0.f, 0.f, 0.f, 0.f);
            tile[p4 * 4 + 0][ci] = f2bs(q.x);
            tile[p4 * 4 + 1][ci] = f2bs(q.y);
            tile[p4 * 4 + 2][ci] = f2bs(q.z);
            tile[p4 * 4 + 3][ci] = f2bs(q.w);
        }
    }
    __syncthreads();

    // phase 2a: int4 stores (8 shorts/lane)
    {
        int seg = t & 7;
        #pragma unroll
        for (int it = 0; it < 2; it++) {
            int pl = (t >> 3) + it * 32;
            int pw = p0 + pl;
            if (pw < SP) {
                short v[8];
                #pragma unroll
                for (int u = 0; u < 8; u++) v[u] = tile[pl][seg * 8 + u];
                *(int4*)(Bt + ((size_t)n * SP + pw) * C + ci0 + seg * 8) = *(int4*)v;
            }
        }
    }

    // phase 2b: per-channel stats (tx = ci) from LDS
    float s = 0.f, s2 = 0.f;
    #pragma unroll
    for (int r = 0; r < 16; r++) {
        int pl = ty4 + r * 4;
        int pw = p0 + pl;
        if (pw < SP) {
            float v = bs2f(tile[pl][tx]);
            s += v; s2 += v * v;
        }
    }
    rs[ty4][tx] = s; rq[ty4][tx] = s2;
    __syncthreads();
    if (ty4 == 0) {
        float ts = rs[0][tx] + rs[1][tx] + rs[2][tx] + rs[3][tx];
        float tq = rq[0][tx] + rq[1][tx] + rq[2][tx] + rq[3][tx];
        atomicAdd(&sum[ci0 + tx], ts);
        atomicAdd(&sq[ci0 + tx], tq);
    }
}

// ---------------- affine transpose (bf16, VMEM-wide): h2 -> B3t ----------------
// in[n][C][SP] bf16 -> Bt[(n*SP+p)][C] bf16 with per-channel affine.
__global__ __launch_bounds__(256) void affine_transpose_bf16_kernel(
    const bf16* __restrict__ in, const float* __restrict__ scale,
    const float* __restrict__ shift, short* __restrict__ Bt,
    int C, int SP) {
    __shared__ short tile[64][66];
    int n = blockIdx.z;
    int ci0 = blockIdx.y * 64;
    int p0 = blockIdx.x * 64;
    int t = threadIdx.x;

    // phase 1: int2 (4 shorts) loads along p, affine, scattered LDS writes
    {
        int p4 = t & 15;
        int cib = t >> 4;
        int p = p0 + p4 * 4;
        bool pok = (p + 3) < SP;          // SP%4==0
        #pragma unroll
        for (int it = 0; it < 4; it++) {
            int ci = cib + it * 16;
            short v[4] = {0, 0, 0, 0};
            if (pok) *(int2*)v = *(const int2*)(in + ((size_t)n * C + ci0 + ci) * SP + p);
            float sc = scale[ci0 + ci], sh = shift[ci0 + ci];
            #pragma unroll
            for (int j = 0; j < 4; j++)
                tile[p4 * 4 + j][ci] = f2bs(bs2f(v[j]) * sc + sh);
        }
    }
    __syncthreads();

    // phase 2: int4 stores
    {
        int seg = t & 7;
        #pragma unroll
        for (int it = 0; it < 2; it++) {
            int pl = (t >> 3) + it * 32;
            int pw = p0 + pl;
            if (pw < SP) {
                short v[8];
                #pragma unroll
                for (int u = 0; u < 8; u++) v[u] = tile[pl][seg * 8 + u];
                *(int4*)(Bt + ((size_t)n * SP + pw) * C + ci0 + seg * 8) = *(int4*)v;
            }
        }
    }
}

// ---------------- LDS-tiled im2col + affine for conv2 (3x3 s2 p1) ----------------
__global__ __launch_bounds__(256) void im2col_tiled_kernel(
    const bf16* __restrict__ h1, const float* __restrict__ scale,
    const float* __restrict__ shift, short* __restrict__ B2t) {
    __shared__ short tile[16][784];   // 25 KB
    int cb = blockIdx.x;              // 0..15 (16-channel slab)
    int n  = blockIdx.y;              // 0..63
    int ci0 = cb * 16;
    int t = threadIdx.x;

    for (int v = t; v < 16 * 98; v += 256) {
        int ci = v / 98;
        int i8 = (v - ci * 98) * 8;
        short tmp[8];
        *(int4*)tmp = *(const int4*)(h1 + ((size_t)n * 256 + ci0 + ci) * 784 + i8);
        float sc = scale[ci0 + ci], sh = shift[ci0 + ci];
        short ov[8];
        #pragma unroll
        for (int k = 0; k < 8; k++) ov[k] = f2bs(bs2f(tmp[k]) * sc + sh);
        *(int4*)&tile[ci][i8] = *(int4*)ov;
    }
    __syncthreads();

    for (int w = t; w < 196 * 18; w += 256) {
        int p = w / 18, seg = w - p * 18;
        int oh = p / 14, ow = p - oh * 14;
        int kbase = seg * 8;
        short vals[8];
        #pragma unroll
        for (int u = 0; u < 8; u++) {
            int kk = kbase + u;
            int ci_l = kk / 9;
            int rr = kk - ci_l * 9;
            int kh = rr / 3, kw = rr - kh * 3;
            int ih = 2 * oh - 1 + kh;
            int iw = 2 * ow - 1 + kw;
            vals[u] = ((unsigned)ih < 28u && (unsigned)iw < 28u)
                          ? tile[ci_l][ih * 28 + iw] : (short)0;
        }
        *(int4*)(B2t + ((size_t)(n * 196 + p)) * 2304 + ci0 * 9 + kbase) = *(int4*)vals;
    }
}

// ---------------- MFMA GEMM (128x128 tile, BK=32, 4 waves, 4x4 16x16x32) ----------------
// FUSE: epilogue adds scv*fscale[m]+fshift[m] (fused residual shortcut).
// HAS_BIAS: out = alpha*(acc + bias[m])  (folded-BN bias for GEMM1).
// BREMAP: B row index = stride-2 subsample of a 28x28 grid (GEMM4 reads raw B1t).
template <int SP, typename TOut, bool HAS_ALPHA, bool FUSE, bool HAS_BIAS, bool BREMAP>
__global__ __launch_bounds__(256) void gemm_kernel(
    const short* __restrict__ A, const short* __restrict__ Bt,
    const float* __restrict__ alpha, TOut* __restrict__ out,
    int M, int K,
    const bf16* __restrict__ scv, const float* __restrict__ fscale,
    const float* __restrict__ fshift, const float* __restrict__ bias) {
    __shared__ short As[128 * 32];
    __shared__ short Bs[128 * 32];
    int t = threadIdx.x;
    int c0 = blockIdx.x * 128;
    int m0 = blockIdx.y * 128;
    int w = t >> 6, l = t & 63;
    int wm = (w >> 1) * 64, wn = (w & 1) * 64;

    int r0 = t >> 2;
    int kg = (t & 3) * 8;

    // B row remap (hoisted: independent of k)
    size_t rowB0, rowB1;
    if (BREMAP) {
        int c = c0 + r0;
        int nn = c / 196, pp = c - nn * 196;
        int oh = pp / 14, ow = pp - oh * 14;
        rowB0 = (size_t)nn * 784 + oh * 56 + ow * 2;
        c += 64;
        nn = c / 196; pp = c - nn * 196;
        oh = pp / 14; ow = pp - oh * 14;
        rowB1 = (size_t)nn * 784 + oh * 56 + ow * 2;
    } else {
        rowB0 = c0 + r0;
        rowB1 = c0 + r0 + 64;
    }

    float4v acc[4][4];
    #pragma unroll
    for (int i = 0; i < 4; i++)
        #pragma unroll
        for (int j = 0; j < 4; j++) acc[i][j] = (float4v)0.f;

    int lm = (l >> 4);
    int lc = l & 15;

    for (int k0 = 0; k0 < K; k0 += 32) {
        int4 av0 = *(const int4*)(A + (size_t)(m0 + r0) * K + k0 + kg);
        int4 av1 = *(const int4*)(A + (size_t)(m0 + r0 + 64) * K + k0 + kg);
        int4 bv0 = *(const int4*)(Bt + rowB0 * K + k0 + kg);
        int4 bv1 = *(const int4*)(Bt + rowB1 * K + k0 + kg);
        __syncthreads();
        *(int4*)&As[r0 * 32 + kg] = av0;
        *(int4*)&As[(r0 + 64) * 32 + kg] = av1;
        *(int4*)&Bs[r0 * 32 + kg] = bv0;
        *(int4*)&Bs[(r0 + 64) * 32 + kg] = bv1;
        __syncthreads();

        short8 af[4], bfr[4];
        #pragma unroll
        for (int i = 0; i < 4; i++)
            af[i] = *(const short8*)&As[(wm + i * 16 + lc) * 32 + lm * 8];
        #pragma unroll
        for (int j = 0; j < 4; j++)
            bfr[j] = *(const short8*)&Bs[(wn + j * 16 + lc) * 32 + lm * 8];
        #pragma unroll
        for (int i = 0; i < 4; i++)
            #pragma unroll
            for (int j = 0; j < 4; j++)
                acc[i][j] = __builtin_amdgcn_mfma_f32_16x16x32_bf16(af[i], bfr[j], acc[i][j], 0, 0, 0);
    }

    #pragma unroll
    for (int i = 0; i < 4; i++) {
        #pragma unroll
        for (int r = 0; r < 4; r++) {
            int m = m0 + wm + i * 16 + lm * 4 + r;
            float a = HAS_ALPHA ? alpha[m] : 1.f;
            float bia = HAS_BIAS ? bias[m] : 0.f;
            float fsc = FUSE ? fscale[m] : 0.f;
            float fsh = FUSE ? fshift[m] : 0.f;
            #pragma unroll
            for (int j = 0; j < 4; j++) {
                int c = c0 + wn + j * 16 + lc;
                int n = c / SP;
                int p = c - n * SP;
                size_t idx = ((size_t)n * M + m) * SP + p;
                float v = acc[i][j][r];
                if (HAS_BIAS) v += bia;
                if (HAS_ALPHA) v *= a;
                if (FUSE) v += toF(scv[idx]) * fsc + fsh;
                stF(&out[idx], v);
            }
        }
    }
}

extern "C" void kernel_launch(void* const* d_in, const int* in_sizes, int n_in,
                              void* d_out, int out_size, void* d_ws, size_t ws_size,
                              hipStream_t stream) {
    const float* x      = (const float*)d_in[0];   // (64,512,28,28)
    const float* bn1_g  = (const float*)d_in[1];
    const float* bn1_b  = (const float*)d_in[2];
    const float* w1     = (const float*)d_in[3];   // (256,512,1,1)
    const float* bn2_g  = (const float*)d_in[4];
    const float* bn2_b  = (const float*)d_in[5];
    const float* w2     = (const float*)d_in[6];   // (256,256,3,3)
    const float* bn3_g  = (const float*)d_in[7];
    const float* bn3_b  = (const float*)d_in[8];
    const float* w3     = (const float*)d_in[9];   // (1024,256,1,1)
    const float* ds_w   = (const float*)d_in[10];  // (1024,512,1,1) NOT ternarized
    const float* dbn_g  = (const float*)d_in[11];
    const float* dbn_b  = (const float*)d_in[12];
    float* out = (float*)d_out;

    const int N = 64, C1 = 512, C2 = 256, C3 = 1024;
    const int SP1 = 784, SP2 = 196;
    const int NT1 = N * SP1;   // 50176
    const int NT2 = N * SP2;   // 12544

    // ---- workspace layout ----
    char* wsb = (char*)d_ws;
    size_t off = 0;
    auto alloc = [&](size_t bytes) { char* p = wsb + off; off += (bytes + 255) & ~(size_t)255; return p; };

    char* pool = alloc((size_t)NT2 * 2304 * 2);   // 57.8 MB: B1t (51.4) / B2t (57.8) / B3t (6.4) time-share
    short* B1t = (short*)pool;                    // raw bf16(x)^T; live until GEMM4
    short* B2t = (short*)pool;                    // created by im2col AFTER GEMM4
    short* B3t = (short*)pool;                    // created after B2t is dead
    bf16*  sc  = (bf16*)alloc((size_t)N * C3 * SP2 * 2);  // 25.7 MB, own region (lives across im2col)

    bf16* h1 = (bf16*)alloc((size_t)N * C2 * SP1 * 2);
    bf16* h2 = (bf16*)alloc((size_t)N * C2 * SP2 * 2);
    short* w1t  = (short*)alloc((size_t)C2 * C1 * 2);
    short* w1f  = (short*)alloc((size_t)C2 * C1 * 2);   // scale-folded w1
    short* w2t  = (short*)alloc((size_t)C2 * C2 * 9 * 2);
    short* w3t  = (short*)alloc((size_t)C3 * C2 * 2);
    short* dswb = (short*)alloc((size_t)C3 * C1 * 2);
    float* alpha1 = (float*)alloc(C2 * 4);
    float* alpha2 = (float*)alloc(C2 * 4);
    float* alpha3 = (float*)alloc(C3 * 4);
    float* bias1  = (float*)alloc(C2 * 4);
    float* scale1 = (float*)alloc(C1 * 4);
    float* shift1 = (float*)alloc(C1 * 4);
    float* scale2 = (float*)alloc(C2 * 4);
    float* shift2 = (float*)alloc(C2 * 4);
    float* scale3 = (float*)alloc(C2 * 4);
    float* shift3 = (float*)alloc(C2 * 4);
    float* scaled = (float*)alloc(C3 * 4);
    float* shiftd = (float*)alloc(C3 * 4);
    float* acc_base = (float*)alloc((size_t)(C1 + C2 + C2 + C3) * 2 * 4);
    float* sum1 = acc_base;            float* sq1 = sum1 + C1;
    float* sum2 = sq1 + C1;            float* sq2 = sum2 + C2;
    float* sum3 = sq2 + C2;            float* sq3 = sum3 + C2;
    float* sumd = sq3 + C2;            float* sqd = sumd + C3;
    (void)ws_size; (void)in_sizes; (void)n_in; (void)out_size;

    // 0) zero BN accumulators
    hipMemsetAsync(acc_base, 0, (size_t)(C1 + C2 + C2 + C3) * 2 * 4, stream);

    // 1) weights
    ternarize_kernel<<<C2, 256, 0, stream>>>(w1, w1t, alpha1, C1);
    ternarize_kernel<<<C2, 256, 0, stream>>>(w2, w2t, alpha2, C2 * 9);
    ternarize_kernel<<<C3, 256, 0, stream>>>(w3, w3t, alpha3, C2);
    f2bf_kernel<<<(C3 * C1 + 255) / 256, 256, 0, stream>>>(ds_w, dswb, C3 * C1);

    // 2) single pass over x: B1t = raw bf16(x)^T + bn1 stats; then finalize + fold into w1
    {
        dim3 grid((SP1 + 63) / 64, C1 / 64, N);
        stats_transpose_kernel<<<grid, 256, 0, stream>>>(x, B1t, sum1, sq1, C1, SP1);
    }
    bn_finalize_kernel<<<(C1 + 255) / 256, 256, 0, stream>>>(sum1, sq1, bn1_g, bn1_b,
                                                             scale1, shift1, C1, (float)(N * SP1));
    foldbias_kernel<<<C2, 256, 0, stream>>>(w1t, scale1, shift1, w1f, bias1, C1);

    // 3) GEMM1: h1 = alpha1 * (w1f . B1t^T + bias1)   M=256 K=512 SP=784
    gemm_kernel<784, bf16, true, false, true, false><<<dim3(NT1 / 128, C2 / 128), 256, 0, stream>>>(
        w1f, B1t, alpha1, h1, C2, C1, nullptr, nullptr, nullptr, bias1);

    // 4) shortcut GEMM4 straight from raw B1t (stride-2 row remap): sc = dswb . B1t_s2^T
    //    M=1024 K=512 SP=196 — must run BEFORE im2col overwrites the pool
    gemm_kernel<196, bf16, false, false, false, true><<<dim3(NT2 / 128, C3 / 128), 256, 0, stream>>>(
        dswb, B1t, nullptr, sc, C3, C1, nullptr, nullptr, nullptr, nullptr);

    // 5) ds bn stats on sc
    bn_sum_kernel<bf16, 4><<<dim3(C3, 4), 256, 0, stream>>>(sc, sumd, sqd, C3, SP2, N, 4);
    bn_finalize_kernel<<<(C3 + 255) / 256, 256, 0, stream>>>(sumd, sqd, dbn_g, dbn_b,
                                                             scaled, shiftd, C3, (float)(N * SP2));

    // 6) bn2 stats + LDS-tiled im2col (B2t overwrites pool — B1t dead now)
    bn_sum_kernel<bf16, 8><<<dim3(C2, 8), 256, 0, stream>>>(h1, sum2, sq2, C2, SP1, N, 8);
    bn_finalize_kernel<<<(C2 + 255) / 256, 256, 0, stream>>>(sum2, sq2, bn2_g, bn2_b,
                                                             scale2, shift2, C2, (float)(N * SP1));
    im2col_tiled_kernel<<<dim3(16, 64), 256, 0, stream>>>(h1, scale2, shift2, B2t);

    // 7) GEMM2: h2 = alpha2 * (w2t . B2t^T)   M=256 K=2304 SP=196
    gemm_kernel<196, bf16, true, false, false, false><<<dim3(NT2 / 128, C2 / 128), 256, 0, stream>>>(
        w2t, B2t, alpha2, h2, C2, C2 * 9, nullptr, nullptr, nullptr, nullptr);

    // 8) bn3 stats + B3t = bn3(h2)^T (vectorized transpose)
    bn_sum_kernel<bf16, 4><<<dim3(C2, 4), 256, 0, stream>>>(h2, sum3, sq3, C2, SP2, N, 4);
    bn_finalize_kernel<<<(C2 + 255) / 256, 256, 0, stream>>>(sum3, sq3, bn3_g, bn3_b,
                                                             scale3, shift3, C2, (float)(N * SP2));
    {
        dim3 grid((SP2 + 63) / 64, C2 / 64, N);
        affine_transpose_bf16_kernel<<<grid, 256, 0, stream>>>(
            h2, scale3, shift3, B3t, C2, SP2);
    }

    // 9) GEMM3 with fused residual: out = alpha3*(w3t . B3t^T) + sc*scaled + shiftd
    gemm_kernel<196, float, true, true, false, false><<<dim3(NT2 / 128, C3 / 128), 256, 0, stream>>>(
        w3t, B3t, alpha3, out, C3, C2, sc, scaled, shiftd, nullptr);
}